// Round 4
// baseline (2799.928 us; speedup 1.0000x reference)
//
#include <hip/hip_runtime.h>

// LSTM_RNN: B=8192, T=2048, H=51, 2-layer LSTM + linear head.
// R8: split-phase 2-barrier schedule to break MFMA/VALU phase lockstep
// (R7 counters: VALU-issue ~1430 cyc + MFMA-pipe ~900 cyc per SIMD-step,
// measured step 3150 => pipes nearly serial). Each step:
//   bar1 | L1: issue 8 MFMA (h1(k-1),x(k)) ; L2: issue 8 h1-part MFMA (A)
//        |   + L2: DEFERRED activation of prev completed acc -> h2(k-2) (B)
//   bar2 | L2: read h2(k-2), issue 8 h2-part MFMA (C, acc ping-pong P/Q
//        |   carried across barriers) ; L1: activation -> write h1(k), x(k+1)
// MFMA issue is non-blocking, so each window overlaps MFMA pipe with the
// other role's VALU. Single LDS buffers (write/read separated by exactly one
// barrier). y rides gate-3 pad col; drained from old acc at window-1 (k-3),
// covers y(T-1) with no tail flush. Everything else as R7: packed-f32
// activation math, fused i*g pair-rcp, batch-4 f-rcp, pre-scaled cell state,
// fused sigma(o)*tanh(c), fp16 MFMA with x/bias K-slots, ROWW=72, s_setprio.

#define B_TOT 8192
#define T_LEN 2048
#define MR    16
#define ROWW  72            // f16 per row: [h 0..50][x 51][1.0 52][0 ..63][pad]
#define HB    (MR*ROWW)     // 1152 f16 per buffer
#define KITER 2052          // unified iter count (even, >= T_LEN+3)

typedef _Float16 f16x8 __attribute__((ext_vector_type(8)));
typedef float    f32x4 __attribute__((ext_vector_type(4)));
typedef float    f32x2 __attribute__((ext_vector_type(2)));

#define LOG2E 1.4426950408889634f

static __device__ __forceinline__ float us2f(unsigned short u) {
    unsigned int w = ((unsigned int)u) << 16;
    float f; __builtin_memcpy(&f, &w, 4);
    return f;
}
// load f32 from f32 or bf16 global
static __device__ __forceinline__ float ldf(const void* p, int idx, bool isbf) {
    return isbf ? us2f(((const unsigned short*)p)[idx])
                : ((const float*)p)[idx];
}
static __device__ __forceinline__ void store_y(void* outp, bool isbf, int idx, float v) {
    if (isbf) {
        unsigned int u; __builtin_memcpy(&u, &v, 4);
        u = (u + 0x7FFFu + ((u >> 16) & 1u)) >> 16;
        ((unsigned short*)outp)[idx] = (unsigned short)u;
    } else {
        ((float*)outp)[idx] = v;
    }
}

// Packed LSTM activation + cell/h update (identical math to R7).
// acc[n][r]: n=0 i (-L*z), n=1 f (-L*z), n=2 g (-2L*z), n=3 o (-L*z).
// C[p] = cell state rows {2p,2p+1}, pre-scaled by -2L. h[p] out.
template<bool CLAMP_G>
static __device__ __forceinline__ void lstm_act(const f32x4* acc, f32x2* C, f32x2* h) {
    f32x2 di[2], df[2], dg[2], dox[2];
    #pragma unroll
    for (int p = 0; p < 2; ++p) {
        f32x2 ei, ef, eg, eo;
        #pragma unroll
        for (int e = 0; e < 2; ++e) {
            const int r = 2*p + e;
            ei[e] = __builtin_amdgcn_exp2f(acc[0][r]);
            ef[e] = __builtin_amdgcn_exp2f(acc[1][r]);
            float ag = acc[2][r];
            if (CLAMP_G) ag = __builtin_amdgcn_fmed3f(ag, -30.0f, 30.0f);
            eg[e] = __builtin_amdgcn_exp2f(ag);
            eo[e] = __builtin_amdgcn_exp2f(acc[3][r]);
        }
        di[p]  = ei + 1.0f;
        df[p]  = ef + 1.0f;
        dg[p]  = eg + 1.0f;
        dox[p] = eo + 1.0f;
    }
    f32x2 q[2], sig[2];
    q[0] = di[0]*dg[0];
    q[1] = di[1]*dg[1];
    const float Ri0 = __builtin_amdgcn_rcpf(q[0].x*q[0].y);
    const float Ri1 = __builtin_amdgcn_rcpf(q[1].x*q[1].y);
    sig[0] = (dg[0]*(2.0f*LOG2E) + (-4.0f*LOG2E)) * (q[0].yx * Ri0);
    sig[1] = (dg[1]*(2.0f*LOG2E) + (-4.0f*LOG2E)) * (q[1].yx * Ri1);
    const float pf01 = df[0].x*df[0].y;
    const float pf23 = df[1].x*df[1].y;
    const float Rf   = __builtin_amdgcn_rcpf(pf01*pf23);
    const f32x2 sf0 = df[0].yx * (Rf*pf23);
    const f32x2 sf1 = df[1].yx * (Rf*pf01);
    f32x2 tt[2], m[2];
    {
        const f32x2 Cn = sf0*C[0] + sig[0];
        C[0] = Cn;
        f32x2 e2;
        e2.x = __builtin_amdgcn_exp2f(__builtin_amdgcn_fmed3f(Cn.x, -30.0f, 30.0f));
        e2.y = __builtin_amdgcn_exp2f(__builtin_amdgcn_fmed3f(Cn.y, -30.0f, 30.0f));
        tt[0] = e2 + 1.0f;
        m[0]  = dox[0]*tt[0];
    }
    {
        const f32x2 Cn = sf1*C[1] + sig[1];
        C[1] = Cn;
        f32x2 e2;
        e2.x = __builtin_amdgcn_exp2f(__builtin_amdgcn_fmed3f(Cn.x, -30.0f, 30.0f));
        e2.y = __builtin_amdgcn_exp2f(__builtin_amdgcn_fmed3f(Cn.y, -30.0f, 30.0f));
        tt[1] = e2 + 1.0f;
        m[1]  = dox[1]*tt[1];
    }
    const float Rc = __builtin_amdgcn_rcpf(m[0].x*m[0].y);
    const float Rd = __builtin_amdgcn_rcpf(m[1].x*m[1].y);
    h[0] = (2.0f - tt[0]) * (m[0].yx * Rc);
    h[1] = (2.0f - tt[1]) * (m[1].yx * Rd);
}

__global__ __launch_bounds__(512, 4)
void lstm2_kernel(const void* __restrict__ xin,
                  const void* __restrict__ Wih1, const void* __restrict__ Whh1,
                  const void* __restrict__ bih1, const void* __restrict__ bhh1,
                  const void* __restrict__ Wih2, const void* __restrict__ Whh2,
                  const void* __restrict__ bih2, const void* __restrict__ bhh2,
                  const void* __restrict__ Wlin, const void* __restrict__ blin,
                  void* __restrict__ outp)
{
    const int tid  = threadIdx.x;
    const int wset = tid >> 8;         // 0: layer-1 waves, 1: layer-2 waves
    const int wv   = (tid >> 6) & 3;   // j-slice within set
    const int ln   = tid & 63;
    const int lid  = ln & 15;
    const int quad = ln >> 4;
    const int b0   = blockIdx.x * MR;
    const int jcol = 13*wv + lid;
    const bool valid = (lid < 13) && (jcol < 51);
    const bool ylane = (wv == 3) && (lid == 12);   // pad col 51 -> y head

    __shared__ alignas(16) _Float16 hx [HB];   // h1 + x/1.0 K-slots (single)
    __shared__ alignas(16) _Float16 h2b[HB];   // h2 (single)

    // ---- dtype sniff (f32 vs bf16 globals), block-uniform ----
    bool isbf;
    {
        const unsigned short* xu = (const unsigned short*)xin;
        int cnt = 0;
        #pragma unroll
        for (int i = 0; i < 64; i += 2) {
            unsigned e = (xu[i] >> 7) & 0xFFu;
            cnt += (e >= 115u && e <= 131u) ? 1 : 0;
        }
        isbf = (cnt >= 16);
    }

    // ---- init LDS ----
    for (int i = tid; i < HB; i += 512) {
        hx[i]  = (_Float16)0.0f;
        h2b[i] = (_Float16)0.0f;
    }
    __syncthreads();
    if (tid < MR) {
        hx[tid*ROWW + 52] = (_Float16)1.0f;                              // bias
        hx[tid*ROWW + 51] = (_Float16)ldf(xin, (b0 + tid)*T_LEN, isbf);  // x(0)
    }
    // (first in-loop bar1 publishes these)

    if (wset == 0) {
        // ================= LAYER-1 WAVES =================
        f16x8 B1[4][2];
        #pragma unroll
        for (int n = 0; n < 4; ++n) {
            const int g = 51*n + jcol;
            const float sn = (n == 2) ? -2.0f*LOG2E : -LOG2E;
            #pragma unroll
            for (int kb = 0; kb < 2; ++kb) {
                f16x8 f;
                #pragma unroll
                for (int j8 = 0; j8 < 8; ++j8) {
                    const int k = kb*32 + quad*8 + j8;
                    float v = 0.0f;
                    if (valid) {
                        if (k < 51)       v = sn * ldf(Whh1, g*51 + k, isbf);
                        else if (k == 51) v = sn * ldf(Wih1, g, isbf);
                        else if (k == 52) v = sn * (ldf(bih1, g, isbf) + ldf(bhh1, g, isbf));
                    }
                    f[j8] = (_Float16)v;
                }
                B1[n][kb] = f;
            }
        }
        f32x2 c1[2] = {{0.0f, 0.0f}, {0.0f, 0.0f}};
        f32x4 acc1[4];

        for (int k = 0; k < KITER; ++k) {
            __syncthreads();                         // bar1
            const bool run = (k < T_LEN);
            const bool xl  = run && (tid < MR) && (k + 1 < T_LEN);
            float xnext = 0.0f;
            if (run) {
                if (xl) xnext = ldf(xin, (b0 + tid)*T_LEN + k + 1, isbf);
                const _Float16* hp = &hx[lid*ROWW + quad*8];
                const f16x8 a0 = *(const f16x8*)(hp);
                const f16x8 a1 = *(const f16x8*)(hp + 32);
                __builtin_amdgcn_s_setprio(1);
                #pragma unroll
                for (int n = 0; n < 4; ++n) {
                    f32x4 z = {0.0f, 0.0f, 0.0f, 0.0f};
                    z       = __builtin_amdgcn_mfma_f32_16x16x32_f16(a0, B1[n][0], z, 0,0,0);
                    acc1[n] = __builtin_amdgcn_mfma_f32_16x16x32_f16(a1, B1[n][1], z, 0,0,0);
                }
                __builtin_amdgcn_s_setprio(0);
            }
            __syncthreads();                         // bar2
            if (run) {
                f32x2 h[2];
                lstm_act<false>(acc1, c1, h);        // VALU overlaps L2's C-MFMAs
                if (valid) {
                    _Float16* hw = &hx[(quad*4)*ROWW + jcol];
                    hw[0*ROWW] = (_Float16)h[0].x;
                    hw[1*ROWW] = (_Float16)h[0].y;
                    hw[2*ROWW] = (_Float16)h[1].x;
                    hw[3*ROWW] = (_Float16)h[1].y;
                }
                if (xl) hx[tid*ROWW + 51] = (_Float16)xnext;
            }
        }
    } else {
        // ================= LAYER-2 WAVES =================
        f16x8 B2i[4][2], B2h[4][2];
        #pragma unroll
        for (int n = 0; n < 4; ++n) {
            const int g = 51*n + jcol;
            const float sn = (n == 2) ? -2.0f*LOG2E : -LOG2E;
            #pragma unroll
            for (int kb = 0; kb < 2; ++kb) {
                f16x8 fi, fh;
                #pragma unroll
                for (int j8 = 0; j8 < 8; ++j8) {
                    const int k = kb*32 + quad*8 + j8;
                    float vi = 0.0f, vh = 0.0f;
                    if (valid) {
                        if (k < 51) {
                            vi = sn * ldf(Wih2, g*51 + k, isbf);
                            vh = sn * ldf(Whh2, g*51 + k, isbf);
                        } else if (k == 52) {
                            vi = sn * (ldf(bih2, g, isbf) + ldf(bhh2, g, isbf));
                        }
                    } else if (ylane && n == 3) {
                        if (k < 51)       vh = ldf(Wlin, k, isbf);
                        else if (k == 52) vi = ldf(blin, 0, isbf);
                    }
                    fi[j8] = (_Float16)vi; fh[j8] = (_Float16)vh;
                }
                B2i[n][kb] = fi; B2h[n][kb] = fh;
            }
        }
        f32x2 c2[2] = {{0.0f, 0.0f}, {0.0f, 0.0f}};
        f32x4 accP[4], accQ[4];

        // One iteration: AN = acc being built (A+C phases), AO = completed acc
        // from the previous iteration (B phase: y-drain + deferred act).
        #define L2STEP(KV, AN, AO) do {                                          \
            const int k_ = (KV);                                                 \
            __syncthreads();  /* bar1 */                                         \
            const bool mf_ = (k_ >= 1) && (k_ <= T_LEN + 1);                     \
            if (mf_) {        /* A: h1-part MFMAs for gates(k-1) */              \
                const _Float16* h1p_ = &hx[lid*ROWW + quad*8];                   \
                const f16x8 p0_ = *(const f16x8*)(h1p_);                         \
                const f16x8 p1_ = *(const f16x8*)(h1p_ + 32);                    \
                __builtin_amdgcn_s_setprio(1);                                   \
                _Pragma("unroll")                                                \
                for (int n = 0; n < 4; ++n) {                                    \
                    f32x4 z_ = {0.0f, 0.0f, 0.0f, 0.0f};                         \
                    z_    = __builtin_amdgcn_mfma_f32_16x16x32_f16(p0_, B2i[n][0], z_, 0,0,0); \
                    AN[n] = __builtin_amdgcn_mfma_f32_16x16x32_f16(p1_, B2i[n][1], z_, 0,0,0); \
                }                                                                \
                __builtin_amdgcn_s_setprio(0);                                   \
            }                                                                    \
            if (ylane && k_ >= 3 && k_ <= T_LEN + 2) {  /* y(k-3) from AO */     \
                _Pragma("unroll")                                                \
                for (int r = 0; r < 4; ++r)                                      \
                    store_y(outp, isbf, (b0 + quad*4 + r)*T_LEN + (k_ - 3), AO[3][r]); \
            }                                                                    \
            if (k_ >= 2 && k_ <= T_LEN + 1) {  /* B: deferred act -> h2(k-2) */  \
                f32x2 hh_[2];                                                    \
                lstm_act<true>(AO, c2, hh_);   /* VALU overlaps A's MFMAs */     \
                if (valid) {                                                     \
                    _Float16* hw_ = &h2b[(quad*4)*ROWW + jcol];                  \
                    hw_[0*ROWW] = (_Float16)hh_[0].x;                            \
                    hw_[1*ROWW] = (_Float16)hh_[0].y;                            \
                    hw_[2*ROWW] = (_Float16)hh_[1].x;                            \
                    hw_[3*ROWW] = (_Float16)hh_[1].y;                            \
                }                                                                \
            }                                                                    \
            __syncthreads();  /* bar2 */                                         \
            if (mf_) {        /* C: h2-part MFMAs, reads h2(k-2) just written */ \
                const _Float16* h2p_ = &h2b[lid*ROWW + quad*8];                  \
                const f16x8 q0_ = *(const f16x8*)(h2p_);                         \
                const f16x8 q1_ = *(const f16x8*)(h2p_ + 32);                    \
                __builtin_amdgcn_s_setprio(1);                                   \
                _Pragma("unroll")                                                \
                for (int n = 0; n < 4; ++n) {                                    \
                    AN[n] = __builtin_amdgcn_mfma_f32_16x16x32_f16(q0_, B2h[n][0], AN[n], 0,0,0); \
                    AN[n] = __builtin_amdgcn_mfma_f32_16x16x32_f16(q1_, B2h[n][1], AN[n], 0,0,0); \
                }                                                                \
                __builtin_amdgcn_s_setprio(0);                                   \
            }                                                                    \
        } while (0)

        for (int kp = 0; kp < KITER/2; ++kp) {
            L2STEP(2*kp,     accP, accQ);
            L2STEP(2*kp + 1, accQ, accP);
        }
        #undef L2STEP
    }
}

extern "C" void kernel_launch(void* const* d_in, const int* in_sizes, int n_in,
                              void* d_out, int out_size, void* d_ws, size_t ws_size,
                              hipStream_t stream) {
    (void)in_sizes; (void)n_in; (void)out_size; (void)d_ws; (void)ws_size;
    dim3 grid(B_TOT / MR), block(512);
    lstm2_kernel<<<grid, block, 0, stream>>>(
        d_in[0], d_in[1], d_in[2], d_in[3], d_in[4], d_in[5],
        d_in[6], d_in[7], d_in[8], d_in[9], d_in[10], d_out);
}